// Round 6
// baseline (13567.134 us; speedup 1.0000x reference)
//
#include <hip/hip_runtime.h>

typedef unsigned short u16;
typedef unsigned long long u64;
typedef float f32x4 __attribute__((ext_vector_type(4)));
typedef short s16x8 __attribute__((ext_vector_type(8)));

#define B_ 64
#define T_ 512
#define I_ 512
#define H_ 1024
#define NBLK 64
#define NTHR 256
#define WIN 16

// workspace layout (bytes)
#define OFF_CNT 0
#define OFF_SBF 1024                    // s-state bf16, frag layout [4 m][32 kc][64 lane]x16B = 131072
#define OFF_RS  (OFF_SBF + 131072)      // r*s bf16, frag layout               = 131072
#define OFF_U   (OFF_RS + 131072)       // bf16 U row-major [3][1024][1024]    = 6291456
#define OFF_W   (OFF_U + 6291456)       // bf16 W row-major [3][1024][512]     = 3145728
#define OFF_PJ  (OFF_W + 3145728)       // proj f32 [64 blk][16 t][4 w][3 g][64 lane]x16B = 12582912

__device__ __forceinline__ u16 f2bf(float f) {
  unsigned u = __float_as_uint(f);
  return (u16)((u + 0x7FFFu + ((u >> 16) & 1u)) >> 16);
}

__device__ __forceinline__ s16x8 pack8(float4 a, float4 b) {
  s16x8 r;
  r[0] = (short)f2bf(a.x); r[1] = (short)f2bf(a.y);
  r[2] = (short)f2bf(a.z); r[3] = (short)f2bf(a.w);
  r[4] = (short)f2bf(b.x); r[5] = (short)f2bf(b.y);
  r[6] = (short)f2bf(b.z); r[7] = (short)f2bf(b.w);
  return r;
}

__global__ void prep_kernel(const float* __restrict__ s0,
                            const float* __restrict__ Wz, const float* __restrict__ Wr,
                            const float* __restrict__ Ws, const float* __restrict__ Uz,
                            const float* __restrict__ Ur, const float* __restrict__ Us,
                            char* __restrict__ ws) {
  u16* ubf = (u16*)(ws + OFF_U);
  u16* wbf = (u16*)(ws + OFF_W);
  int tid = blockIdx.x * blockDim.x + threadIdx.x;
  int stride = gridDim.x * blockDim.x;
  const int NU = H_ * H_;
  for (int i = tid; i < NU; i += stride) {
    ubf[i] = f2bf(Uz[i]);
    ubf[NU + i] = f2bf(Ur[i]);
    ubf[2 * NU + i] = f2bf(Us[i]);
  }
  const int NW = H_ * I_;
  for (int i = tid; i < NW; i += stride) {
    wbf[i] = f2bf(Wz[i]);
    wbf[NW + i] = f2bf(Wr[i]);
    wbf[2 * NW + i] = f2bf(Ws[i]);
  }
  // s0 -> frag-layout bf16 state: frag[m][kc][lane] 16B; A-frag: row=l&15, k=kc*32+(l>>4)*8
  for (int f = tid; f < 4 * 32 * 64; f += stride) {
    int kc = (f >> 6) & 31, l = f & 63;
    int b = (f >> 11) * 16 + (l & 15);
    int k = kc * 32 + (l >> 4) * 8;
    const float* sp = s0 + (u64)b * H_ + k;
    ushort4 lo, hi;
    lo.x = f2bf(sp[0]); lo.y = f2bf(sp[1]); lo.z = f2bf(sp[2]); lo.w = f2bf(sp[3]);
    hi.x = f2bf(sp[4]); hi.y = f2bf(sp[5]); hi.z = f2bf(sp[6]); hi.w = f2bf(sp[7]);
    ushort4* dst = (ushort4*)(ws + OFF_SBF + (u64)f * 16);
    dst[0] = lo; dst[1] = hi;
  }
}

// ---- grid barrier: single monotonic counter, no release hop.
// Producer data travels: plain store -> fence(release)=buffer_wbl2 -> arrive.
// Consumer: poll count -> fence(acquire)=buffer_inv -> plain (L2-shared) loads.
__device__ __forceinline__ void bar_arrive(unsigned* cnt) {
  __builtin_amdgcn_fence(__ATOMIC_RELEASE, "agent");
  __syncthreads();
  if (threadIdx.x == 0)
    __hip_atomic_fetch_add(cnt, 1u, __ATOMIC_RELAXED, __HIP_MEMORY_SCOPE_AGENT);
}
__device__ __forceinline__ void bar_wait(unsigned* cnt, unsigned target) {
  if (threadIdx.x == 0) {
    while (__hip_atomic_load(cnt, __ATOMIC_RELAXED, __HIP_MEMORY_SCOPE_AGENT) < target)
      __builtin_amdgcn_s_sleep(2);
  }
  __syncthreads();
  __builtin_amdgcn_fence(__ATOMIC_ACQUIRE, "agent");
}

#define SWZ(row, byteInRow, rowShift) \
  (((((row) << (rowShift)) + (byteInRow))) ^ (((row) & 7) << 4))

__device__ __forceinline__ void window_proj(int t0, int jb, int wave, int lane,
                                            const float* __restrict__ x,
                                            const u16* w_lds, char* __restrict__ ws) {
  const int ln15 = lane & 15, kg = lane >> 4;
  for (int tt = 0; tt < WIN; ++tt) {
    f32x4 ac0 = {0.f,0.f,0.f,0.f}, ac1 = {0.f,0.f,0.f,0.f}, ac2 = {0.f,0.f,0.f,0.f};
    const float* xp0 = x + ((u64)(wave * 16 + ln15) * T_ + (t0 + tt)) * I_ + kg * 8;
    #pragma unroll
    for (int kc = 0; kc < 16; ++kc) {
      float4 xa = *(const float4*)(xp0 + kc * 32);
      float4 xb = *(const float4*)(xp0 + kc * 32 + 4);
      s16x8 a = pack8(xa, xb);
      const int cb = kc * 64 + kg * 16;
      s16x8 b0 = *(const s16x8*)((const char*)w_lds + SWZ(ln15, cb, 10));
      s16x8 b1 = *(const s16x8*)((const char*)w_lds + SWZ(16 + ln15, cb, 10));
      s16x8 b2 = *(const s16x8*)((const char*)w_lds + SWZ(32 + ln15, cb, 10));
      ac0 = __builtin_amdgcn_mfma_f32_16x16x32_bf16(a, b0, ac0, 0, 0, 0);
      ac1 = __builtin_amdgcn_mfma_f32_16x16x32_bf16(a, b1, ac1, 0, 0, 0);
      ac2 = __builtin_amdgcn_mfma_f32_16x16x32_bf16(a, b2, ac2, 0, 0, 0);
    }
    f32x4* pj = (f32x4*)(ws + OFF_PJ + (u64)jb * 196608 + (u64)((tt * 4 + wave) * 3) * 1024 + lane * 16);
    pj[0]   = ac0;
    pj[64]  = ac1;
    pj[128] = ac2;
  }
}

__global__ __launch_bounds__(NTHR, 1) void scan_kernel(
    const float* __restrict__ x, const float* __restrict__ mask,
    const float* __restrict__ bz, const float* __restrict__ br,
    const float* __restrict__ bs, const float* __restrict__ s0,
    char* __restrict__ ws, float* __restrict__ out) {

  __shared__ u16 u_lds[3 * 16 * 1024];   // 96KB  U slices (swizzled, resident all steps)
  __shared__ u16 w_lds[3 * 16 * 512];    // 48KB  W slices (swizzled, resident)
  __shared__ u16 tbf[4][16][16];         // 2KB   per-wave bf16 transpose tile
  __shared__ float tf32[4][16][16];      // 4KB   per-wave f32 transpose tile

  s16x8* fsv = (s16x8*)(ws + OFF_SBF);
  s16x8* frv = (s16x8*)(ws + OFF_RS);
  const u16* ubf = (const u16*)(ws + OFF_U);
  const u16* wbf = (const u16*)(ws + OFF_W);
  unsigned* cnt = (unsigned*)(ws + OFF_CNT);

  const int tid = threadIdx.x;
  const int jb = blockIdx.x;
  const int h0 = jb * 16;
  const int lane = tid & 63;
  const int wave = tid >> 6;
  const int ln15 = lane & 15;
  const int kg = lane >> 4;
  const int h = h0 + ln15;

  // one-time LDS preload of U and W slices (LDS is immune to the L2 invalidations below)
  for (int e = tid * 8; e < 3 * 16 * 1024; e += NTHR * 8) {
    int row = e >> 10, k = e & 1023;
    int g = row >> 4, hi = row & 15;
    uint4 v = *(const uint4*)(ubf + ((u64)(g * H_ + h0 + hi) * H_ + k));
    *(uint4*)((char*)u_lds + SWZ(row, (k << 1), 11)) = v;
  }
  for (int e = tid * 8; e < 3 * 16 * 512; e += NTHR * 8) {
    int row = e >> 9, k = e & 511;
    int g = row >> 4, hi = row & 15;
    uint4 v = *(const uint4*)(wbf + ((u64)(g * H_ + h0 + hi) * I_ + k));
    *(uint4*)((char*)w_lds + SWZ(row, (k << 1), 10)) = v;
  }
  const float bzv = bz[h];
  const float brv = br[h];
  const float bsv = bs[h];
  float sreg[4];
  #pragma unroll
  for (int j = 0; j < 4; ++j)
    sreg[j] = s0[(u64)(wave * 16 + kg * 4 + j) * H_ + h];
  __syncthreads();

  window_proj(0, jb, wave, lane, x, w_lds, ws);
  unsigned bidx = 0;

  for (int t = 0; t < T_; ++t) {
    const int tt = t & (WIN - 1);
    // independent per-step data (proj block-private/L2, mask read-only) — issue early
    const f32x4* pjb = (const f32x4*)(ws + OFF_PJ + (u64)jb * 196608 + (u64)((tt * 4 + wave) * 3) * 1024);
    f32x4 p0 = pjb[lane];
    f32x4 p1 = pjb[64 + lane];
    f32x4 p2 = pjb[128 + lane];
    float mv[4];
    #pragma unroll
    for (int j = 0; j < 4; ++j) mv[j] = mask[(u64)(wave * 16 + kg * 4 + j) * T_ + t];

    // ---------- phase 1: z, r ----------
    s16x8 aS[32];
    {
      const s16x8* base = fsv + (u64)(wave * 32) * 64 + lane;
      #pragma unroll
      for (int kc = 0; kc < 32; ++kc) aS[kc] = base[kc * 64];
    }
    f32x4 accz = {0.f,0.f,0.f,0.f}, accr = {0.f,0.f,0.f,0.f};
    #pragma unroll
    for (int kc = 0; kc < 32; ++kc) {
      const int cb = kc * 64 + kg * 16;
      s16x8 b0 = *(const s16x8*)((const char*)u_lds + SWZ(ln15, cb, 11));
      s16x8 b1 = *(const s16x8*)((const char*)u_lds + SWZ(16 + ln15, cb, 11));
      accz = __builtin_amdgcn_mfma_f32_16x16x32_bf16(aS[kc], b0, accz, 0, 0, 0);
      accr = __builtin_amdgcn_mfma_f32_16x16x32_bf16(aS[kc], b1, accr, 0, 0, 0);
    }
    float zv[4];
    #pragma unroll
    for (int j = 0; j < 4; ++j) {
      float z = 1.f / (1.f + __expf(-(accz[j] + p0[j] + bzv)));
      float r = 1.f / (1.f + __expf(-(accr[j] + p1[j] + brv)));
      zv[j] = z;
      tbf[wave][kg * 4 + j][ln15] = f2bf(sreg[j] * r);   // wave-local transpose tile
    }
    if (lane < 32) {  // tile -> frag layout, plain store (wb'd by release fence)
      s16x8 v = *(const s16x8*)&tbf[wave][lane & 15][(lane >> 4) * 8];
      frv[(u64)(wave * 32 + (jb >> 1)) * 64 + lane + 32 * (jb & 1)] = v;
    }
    ++bidx;
    bar_arrive(cnt);
    bar_wait(cnt, NBLK * bidx);

    // ---------- phase 2: s_hat, state update ----------
    s16x8 aR[32];
    {
      const s16x8* base = frv + (u64)(wave * 32) * 64 + lane;
      #pragma unroll
      for (int kc = 0; kc < 32; ++kc) aR[kc] = base[kc * 64];
    }
    f32x4 accs = {0.f,0.f,0.f,0.f};
    #pragma unroll
    for (int kc = 0; kc < 32; ++kc) {
      const int cb = kc * 64 + kg * 16;
      s16x8 b2 = *(const s16x8*)((const char*)u_lds + SWZ(32 + ln15, cb, 11));
      accs = __builtin_amdgcn_mfma_f32_16x16x32_bf16(aR[kc], b2, accs, 0, 0, 0);
    }
    #pragma unroll
    for (int j = 0; j < 4; ++j) {
      float shat = fmaxf(accs[j] + p2[j] + bsv, 0.f);
      float sn = (1.f - zv[j]) * sreg[j] + zv[j] * shat;
      float sf = sreg[j] + mv[j] * (sn - sreg[j]);
      sreg[j] = sf;
      tf32[wave][kg * 4 + j][ln15] = sf;
      tbf[wave][kg * 4 + j][ln15] = f2bf(sf);
    }
    {  // coalesced out store: 16B contiguous in h per (b,t)
      f32x4 o = *(const f32x4*)&tf32[wave][lane >> 2][(lane & 3) * 4];
      f32x4* op = (f32x4*)(out + ((u64)(wave * 16 + (lane >> 2)) * T_ + t) * H_ + h0 + (lane & 3) * 4);
      __builtin_nontemporal_store(o, op);
    }
    if (lane < 32) {  // new state -> frag layout, plain store
      s16x8 v = *(const s16x8*)&tbf[wave][lane & 15][(lane >> 4) * 8];
      fsv[(u64)(wave * 32 + (jb >> 1)) * 64 + lane + 32 * (jb & 1)] = v;
    }
    ++bidx;
    bar_arrive(cnt);
    if (((t + 1) & (WIN - 1)) == 0 && (t + 1) < T_)
      window_proj(t + 1, jb, wave, lane, x, w_lds, ws);  // overlapped with barrier slack
    bar_wait(cnt, NBLK * bidx);
  }
}

extern "C" void kernel_launch(void* const* d_in, const int* in_sizes, int n_in,
                              void* d_out, int out_size, void* d_ws, size_t ws_size,
                              hipStream_t stream) {
  const float* x   = (const float*)d_in[0];
  const float* msk = (const float*)d_in[1];
  const float* s0  = (const float*)d_in[2];
  const float* Ws_ = (const float*)d_in[3];
  const float* Wr_ = (const float*)d_in[4];
  const float* Wz_ = (const float*)d_in[5];
  const float* Us_ = (const float*)d_in[6];
  const float* Ur_ = (const float*)d_in[7];
  const float* Uz_ = (const float*)d_in[8];
  const float* bs_ = (const float*)d_in[9];
  const float* br_ = (const float*)d_in[10];
  const float* bz_ = (const float*)d_in[11];
  float* out = (float*)d_out;
  char* ws = (char*)d_ws;

  (void)hipMemsetAsync(d_ws, 0, 1024, stream);  // barrier counter
  hipLaunchKernelGGL(prep_kernel, dim3(1024), dim3(256), 0, stream,
                     s0, Wz_, Wr_, Ws_, Uz_, Ur_, Us_, ws);
  hipLaunchKernelGGL(scan_kernel, dim3(NBLK), dim3(NTHR), 0, stream,
                     x, msk, bz_, br_, bs_, s0, ws, out);
}

// Round 7
// 10444.116 us; speedup vs baseline: 1.2990x; 1.2990x over previous
//
#include <hip/hip_runtime.h>

typedef unsigned short u16;
typedef unsigned long long u64;
typedef float f32x4 __attribute__((ext_vector_type(4)));
typedef short s16x8 __attribute__((ext_vector_type(8)));

#define B_ 64
#define T_ 512
#define I_ 512
#define H_ 1024
#define NBLK 64
#define NTHR 256
#define WIN 16

// workspace layout (bytes)
#define OFF_FLG 0                       // 64 flags, one per block, 128B stride = 8192
#define OFF_SBF 8192                    // s-state bf16, frag layout [4 m][32 kc][64 lane]x16B = 131072
#define OFF_RS  (OFF_SBF + 131072)      // r*s bf16, frag layout               = 131072
#define OFF_U   (OFF_RS + 131072)       // bf16 U row-major [3][1024][1024]    = 6291456
#define OFF_W   (OFF_U + 6291456)       // bf16 W row-major [3][1024][512]     = 3145728
#define OFF_PJ  (OFF_W + 3145728)       // proj f32 [64 blk][16 t][4 w][3 g][64 lane]x16B = 12582912

__device__ __forceinline__ u16 f2bf(float f) {
  unsigned u = __float_as_uint(f);
  return (u16)((u + 0x7FFFu + ((u >> 16) & 1u)) >> 16);
}

union FR { u64 q[2]; s16x8 v; };

__device__ __forceinline__ s16x8 pack8(float4 a, float4 b) {
  s16x8 r;
  r[0] = (short)f2bf(a.x); r[1] = (short)f2bf(a.y);
  r[2] = (short)f2bf(a.z); r[3] = (short)f2bf(a.w);
  r[4] = (short)f2bf(b.x); r[5] = (short)f2bf(b.y);
  r[6] = (short)f2bf(b.z); r[7] = (short)f2bf(b.w);
  return r;
}

__global__ void prep_kernel(const float* __restrict__ s0,
                            const float* __restrict__ Wz, const float* __restrict__ Wr,
                            const float* __restrict__ Ws, const float* __restrict__ Uz,
                            const float* __restrict__ Ur, const float* __restrict__ Us,
                            char* __restrict__ ws) {
  u16* ubf = (u16*)(ws + OFF_U);
  u16* wbf = (u16*)(ws + OFF_W);
  int tid = blockIdx.x * blockDim.x + threadIdx.x;
  int stride = gridDim.x * blockDim.x;
  const int NU = H_ * H_;
  for (int i = tid; i < NU; i += stride) {
    ubf[i] = f2bf(Uz[i]);
    ubf[NU + i] = f2bf(Ur[i]);
    ubf[2 * NU + i] = f2bf(Us[i]);
  }
  const int NW = H_ * I_;
  for (int i = tid; i < NW; i += stride) {
    wbf[i] = f2bf(Wz[i]);
    wbf[NW + i] = f2bf(Wr[i]);
    wbf[2 * NW + i] = f2bf(Ws[i]);
  }
  // s0 -> frag-layout bf16 state: frag[m][kc][lane] 16B; A-frag: row=l&15, k=kc*32+(l>>4)*8
  for (int f = tid; f < 4 * 32 * 64; f += stride) {
    int kc = (f >> 6) & 31, l = f & 63;
    int b = (f >> 11) * 16 + (l & 15);
    int k = kc * 32 + (l >> 4) * 8;
    const float* sp = s0 + (u64)b * H_ + k;
    ushort4 lo, hi;
    lo.x = f2bf(sp[0]); lo.y = f2bf(sp[1]); lo.z = f2bf(sp[2]); lo.w = f2bf(sp[3]);
    hi.x = f2bf(sp[4]); hi.y = f2bf(sp[5]); hi.z = f2bf(sp[6]); hi.w = f2bf(sp[7]);
    ushort4* dst = (ushort4*)(ws + OFF_SBF + (u64)f * 16);
    dst[0] = lo; dst[1] = hi;
  }
}

// ---- distributed flag barrier: NO contended RMW.
// Each block relaxed-stores its own flag (own cacheline); wave 0's lane l
// read-polls flag[l]. Shared state travels via sc1 (agent-scope) atomics that
// bypass the non-coherent caches, so no fences are needed anywhere.
__device__ __forceinline__ void bar_signal(unsigned* flags, int jb, unsigned bidx) {
  asm volatile("s_waitcnt vmcnt(0)" ::: "memory");  // drain this wave's sc1 state stores
  __syncthreads();                                   // all waves drained
  if (threadIdx.x == 0)
    __hip_atomic_store(flags + (u64)jb * 32, bidx, __ATOMIC_RELAXED, __HIP_MEMORY_SCOPE_AGENT);
}
__device__ __forceinline__ void bar_poll(unsigned* flags, unsigned bidx) {
  if (threadIdx.x < NBLK) {
    while (__hip_atomic_load(flags + (u64)threadIdx.x * 32,
                             __ATOMIC_RELAXED, __HIP_MEMORY_SCOPE_AGENT) < bidx)
      __builtin_amdgcn_s_sleep(1);
  }
  __syncthreads();
}

#define SWZ(row, byteInRow, rowShift) \
  (((((row) << (rowShift)) + (byteInRow))) ^ (((row) & 7) << 4))

__device__ __forceinline__ void window_proj(int t0, int jb, int wave, int lane,
                                            const float* __restrict__ x,
                                            const u16* w_lds, char* __restrict__ ws) {
  const int ln15 = lane & 15, kg = lane >> 4;
  for (int tt = 0; tt < WIN; ++tt) {
    f32x4 ac0 = {0.f,0.f,0.f,0.f}, ac1 = {0.f,0.f,0.f,0.f}, ac2 = {0.f,0.f,0.f,0.f};
    const float* xp0 = x + ((u64)(wave * 16 + ln15) * T_ + (t0 + tt)) * I_ + kg * 8;
    #pragma unroll
    for (int kc = 0; kc < 16; ++kc) {
      float4 xa = *(const float4*)(xp0 + kc * 32);
      float4 xb = *(const float4*)(xp0 + kc * 32 + 4);
      s16x8 a = pack8(xa, xb);
      const int cb = kc * 64 + kg * 16;
      s16x8 b0 = *(const s16x8*)((const char*)w_lds + SWZ(ln15, cb, 10));
      s16x8 b1 = *(const s16x8*)((const char*)w_lds + SWZ(16 + ln15, cb, 10));
      s16x8 b2 = *(const s16x8*)((const char*)w_lds + SWZ(32 + ln15, cb, 10));
      ac0 = __builtin_amdgcn_mfma_f32_16x16x32_bf16(a, b0, ac0, 0, 0, 0);
      ac1 = __builtin_amdgcn_mfma_f32_16x16x32_bf16(a, b1, ac1, 0, 0, 0);
      ac2 = __builtin_amdgcn_mfma_f32_16x16x32_bf16(a, b2, ac2, 0, 0, 0);
    }
    f32x4* pj = (f32x4*)(ws + OFF_PJ + (u64)jb * 196608 + (u64)((tt * 4 + wave) * 3) * 1024 + lane * 16);
    pj[0]   = ac0;
    pj[64]  = ac1;
    pj[128] = ac2;
  }
}

__global__ __launch_bounds__(NTHR, 1) void scan_kernel(
    const float* __restrict__ x, const float* __restrict__ mask,
    const float* __restrict__ bz, const float* __restrict__ br,
    const float* __restrict__ bs, const float* __restrict__ s0,
    char* __restrict__ ws, float* __restrict__ out) {

  __shared__ u16 u_lds[3 * 16 * 1024];   // 96KB  U slices (swizzled, resident all steps)
  __shared__ u16 w_lds[3 * 16 * 512];    // 48KB  W slices (swizzled, resident)
  __shared__ u16 tbf[4][16][16];         // 2KB   per-wave bf16 transpose tile
  __shared__ float tf32[4][16][16];      // 4KB   per-wave f32 transpose tile

  u64* fsbf = (u64*)(ws + OFF_SBF);
  u64* frs  = (u64*)(ws + OFF_RS);
  const u16* ubf = (const u16*)(ws + OFF_U);
  const u16* wbf = (const u16*)(ws + OFF_W);
  unsigned* flags = (unsigned*)(ws + OFF_FLG);

  const int tid = threadIdx.x;
  const int jb = blockIdx.x;
  const int h0 = jb * 16;
  const int lane = tid & 63;
  const int wave = tid >> 6;
  const int ln15 = lane & 15;
  const int kg = lane >> 4;
  const int h = h0 + ln15;

  // one-time LDS preload of U and W slices
  for (int e = tid * 8; e < 3 * 16 * 1024; e += NTHR * 8) {
    int row = e >> 10, k = e & 1023;
    int g = row >> 4, hi = row & 15;
    uint4 v = *(const uint4*)(ubf + ((u64)(g * H_ + h0 + hi) * H_ + k));
    *(uint4*)((char*)u_lds + SWZ(row, (k << 1), 11)) = v;
  }
  for (int e = tid * 8; e < 3 * 16 * 512; e += NTHR * 8) {
    int row = e >> 9, k = e & 511;
    int g = row >> 4, hi = row & 15;
    uint4 v = *(const uint4*)(wbf + ((u64)(g * H_ + h0 + hi) * I_ + k));
    *(uint4*)((char*)w_lds + SWZ(row, (k << 1), 10)) = v;
  }
  const float bzv = bz[h];
  const float brv = br[h];
  const float bsv = bs[h];
  float sreg[4];
  #pragma unroll
  for (int j = 0; j < 4; ++j)
    sreg[j] = s0[(u64)(wave * 16 + kg * 4 + j) * H_ + h];
  __syncthreads();

  window_proj(0, jb, wave, lane, x, w_lds, ws);
  unsigned bidx = 0;

  for (int t = 0; t < T_; ++t) {
    const int tt = t & (WIN - 1);
    // per-step private data (proj block-private/L2, mask read-only) — issue early
    const f32x4* pjb = (const f32x4*)(ws + OFF_PJ + (u64)jb * 196608 + (u64)((tt * 4 + wave) * 3) * 1024);
    f32x4 p0 = pjb[lane];
    f32x4 p1 = pjb[64 + lane];
    f32x4 p2 = pjb[128 + lane];
    float mv[4];
    #pragma unroll
    for (int j = 0; j < 4; ++j) mv[j] = mask[(u64)(wave * 16 + kg * 4 + j) * T_ + t];

    // ---------- phase 1: z, r ----------
    u64 aS[64];
    {
      const u64* base = fsbf + (u64)(wave * 32) * 128 + lane * 2;
      #pragma unroll
      for (int kc = 0; kc < 32; ++kc) {
        aS[2 * kc]     = __hip_atomic_load(base + kc * 128,     __ATOMIC_RELAXED, __HIP_MEMORY_SCOPE_AGENT);
        aS[2 * kc + 1] = __hip_atomic_load(base + kc * 128 + 1, __ATOMIC_RELAXED, __HIP_MEMORY_SCOPE_AGENT);
      }
    }
    f32x4 accz = {0.f,0.f,0.f,0.f}, accr = {0.f,0.f,0.f,0.f};
    #pragma unroll
    for (int kc = 0; kc < 32; ++kc) {
      FR u; u.q[0] = aS[2 * kc]; u.q[1] = aS[2 * kc + 1];
      const int cb = kc * 64 + kg * 16;
      s16x8 b0 = *(const s16x8*)((const char*)u_lds + SWZ(ln15, cb, 11));
      s16x8 b1 = *(const s16x8*)((const char*)u_lds + SWZ(16 + ln15, cb, 11));
      accz = __builtin_amdgcn_mfma_f32_16x16x32_bf16(u.v, b0, accz, 0, 0, 0);
      accr = __builtin_amdgcn_mfma_f32_16x16x32_bf16(u.v, b1, accr, 0, 0, 0);
    }
    float zv[4];
    #pragma unroll
    for (int j = 0; j < 4; ++j) {
      float z = 1.f / (1.f + __expf(-(accz[j] + p0[j] + bzv)));
      float r = 1.f / (1.f + __expf(-(accr[j] + p1[j] + brv)));
      zv[j] = z;
      tbf[wave][kg * 4 + j][ln15] = f2bf(sreg[j] * r);   // wave-local transpose tile
    }
    __builtin_amdgcn_s_barrier();  // tbf tile complete within wave group (LDS, wave-local rows; cheap)
    if (lane < 32) {  // tile -> frag layout, device-coherent (sc1) store
      FR u;
      u.v = *(const s16x8*)&tbf[wave][lane & 15][(lane >> 4) * 8];
      u64* dst = frs + ((u64)wave * 32 + (jb >> 1)) * 128 + ((u64)lane + 32 * (jb & 1)) * 2;
      __hip_atomic_store(dst,     u.q[0], __ATOMIC_RELAXED, __HIP_MEMORY_SCOPE_AGENT);
      __hip_atomic_store(dst + 1, u.q[1], __ATOMIC_RELAXED, __HIP_MEMORY_SCOPE_AGENT);
    }
    ++bidx;
    bar_signal(flags, jb, bidx);
    bar_poll(flags, bidx);

    // ---------- phase 2: s_hat, state update ----------
    u64 aR[64];
    {
      const u64* base = frs + (u64)(wave * 32) * 128 + lane * 2;
      #pragma unroll
      for (int kc = 0; kc < 32; ++kc) {
        aR[2 * kc]     = __hip_atomic_load(base + kc * 128,     __ATOMIC_RELAXED, __HIP_MEMORY_SCOPE_AGENT);
        aR[2 * kc + 1] = __hip_atomic_load(base + kc * 128 + 1, __ATOMIC_RELAXED, __HIP_MEMORY_SCOPE_AGENT);
      }
    }
    f32x4 accs = {0.f,0.f,0.f,0.f};
    #pragma unroll
    for (int kc = 0; kc < 32; ++kc) {
      FR u; u.q[0] = aR[2 * kc]; u.q[1] = aR[2 * kc + 1];
      const int cb = kc * 64 + kg * 16;
      s16x8 b2 = *(const s16x8*)((const char*)u_lds + SWZ(32 + ln15, cb, 11));
      accs = __builtin_amdgcn_mfma_f32_16x16x32_bf16(u.v, b2, accs, 0, 0, 0);
    }
    #pragma unroll
    for (int j = 0; j < 4; ++j) {
      float shat = fmaxf(accs[j] + p2[j] + bsv, 0.f);
      float sn = (1.f - zv[j]) * sreg[j] + zv[j] * shat;
      float sf = sreg[j] + mv[j] * (sn - sreg[j]);
      sreg[j] = sf;
      tf32[wave][kg * 4 + j][ln15] = sf;
      tbf[wave][kg * 4 + j][ln15] = f2bf(sf);
    }
    __builtin_amdgcn_s_barrier();  // tiles complete
    {  // coalesced out store: 16B contiguous in h per (b,t)
      f32x4 o = *(const f32x4*)&tf32[wave][lane >> 2][(lane & 3) * 4];
      f32x4* op = (f32x4*)(out + ((u64)(wave * 16 + (lane >> 2)) * T_ + t) * H_ + h0 + (lane & 3) * 4);
      __builtin_nontemporal_store(o, op);
    }
    if (lane < 32) {  // new state -> frag layout, sc1 store
      FR u;
      u.v = *(const s16x8*)&tbf[wave][lane & 15][(lane >> 4) * 8];
      u64* dst = fsbf + ((u64)wave * 32 + (jb >> 1)) * 128 + ((u64)lane + 32 * (jb & 1)) * 2;
      __hip_atomic_store(dst,     u.q[0], __ATOMIC_RELAXED, __HIP_MEMORY_SCOPE_AGENT);
      __hip_atomic_store(dst + 1, u.q[1], __ATOMIC_RELAXED, __HIP_MEMORY_SCOPE_AGENT);
    }
    ++bidx;
    bar_signal(flags, jb, bidx);
    if (((t + 1) & (WIN - 1)) == 0 && (t + 1) < T_)
      window_proj(t + 1, jb, wave, lane, x, w_lds, ws);  // overlapped with barrier slack
    bar_poll(flags, bidx);
  }
}

extern "C" void kernel_launch(void* const* d_in, const int* in_sizes, int n_in,
                              void* d_out, int out_size, void* d_ws, size_t ws_size,
                              hipStream_t stream) {
  const float* x   = (const float*)d_in[0];
  const float* msk = (const float*)d_in[1];
  const float* s0  = (const float*)d_in[2];
  const float* Ws_ = (const float*)d_in[3];
  const float* Wr_ = (const float*)d_in[4];
  const float* Wz_ = (const float*)d_in[5];
  const float* Us_ = (const float*)d_in[6];
  const float* Ur_ = (const float*)d_in[7];
  const float* Uz_ = (const float*)d_in[8];
  const float* bs_ = (const float*)d_in[9];
  const float* br_ = (const float*)d_in[10];
  const float* bz_ = (const float*)d_in[11];
  float* out = (float*)d_out;
  char* ws = (char*)d_ws;

  (void)hipMemsetAsync(d_ws, 0, 8192, stream);  // barrier flags
  hipLaunchKernelGGL(prep_kernel, dim3(1024), dim3(256), 0, stream,
                     s0, Wz_, Wr_, Ws_, Uz_, Ur_, Us_, ws);
  hipLaunchKernelGGL(scan_kernel, dim3(NBLK), dim3(NTHR), 0, stream,
                     x, msk, bz_, br_, bs_, s0, ws, out);
}

// Round 8
// 3059.460 us; speedup vs baseline: 4.4345x; 3.4137x over previous
//
#include <hip/hip_runtime.h>

typedef unsigned short u16;
typedef unsigned long long u64;
typedef float f32x4 __attribute__((ext_vector_type(4)));
typedef short s16x8 __attribute__((ext_vector_type(8)));

#define B_ 64
#define T_ 512
#define I_ 512
#define H_ 1024
#define NBLK 256
#define NGRP 4      // batch groups (16 batches each), independent barrier domains
#define NMEM 64     // blocks (h-slices) per group
#define NTHR 256

// workspace layout (bytes)
#define OFF_FLG 0                        // [4 grp][64 member] u32 flags, 128B stride = 32768
#define OFF_SBF 32768                    // s bf16 frags [4 bg][32 kc][64 lane]x16B = 131072
#define OFF_RS  (OFF_SBF + 131072)      // r*s bf16 frags, same layout = 131072
#define OFF_U   (OFF_RS + 131072)       // bf16 U row-major [3][1024][1024] = 6291456
#define OFF_W   (OFF_U + 6291456)       // bf16 W row-major [3][1024][512]  = 3145728

__device__ __forceinline__ u16 f2bf(float f) {
  unsigned u = __float_as_uint(f);
  return (u16)((u + 0x7FFFu + ((u >> 16) & 1u)) >> 16);
}

union FR { u64 q[2]; s16x8 v; };

__device__ __forceinline__ s16x8 pack8(float4 a, float4 b) {
  s16x8 r;
  r[0] = (short)f2bf(a.x); r[1] = (short)f2bf(a.y);
  r[2] = (short)f2bf(a.z); r[3] = (short)f2bf(a.w);
  r[4] = (short)f2bf(b.x); r[5] = (short)f2bf(b.y);
  r[6] = (short)f2bf(b.z); r[7] = (short)f2bf(b.w);
  return r;
}

__global__ void prep_kernel(const float* __restrict__ s0,
                            const float* __restrict__ Wz, const float* __restrict__ Wr,
                            const float* __restrict__ Ws, const float* __restrict__ Uz,
                            const float* __restrict__ Ur, const float* __restrict__ Us,
                            char* __restrict__ ws) {
  u16* ubf = (u16*)(ws + OFF_U);
  u16* wbf = (u16*)(ws + OFF_W);
  int tid = blockIdx.x * blockDim.x + threadIdx.x;
  int stride = gridDim.x * blockDim.x;
  const int NU = H_ * H_;
  for (int i = tid; i < NU; i += stride) {
    ubf[i] = f2bf(Uz[i]);
    ubf[NU + i] = f2bf(Ur[i]);
    ubf[2 * NU + i] = f2bf(Us[i]);
  }
  const int NW = H_ * I_;
  for (int i = tid; i < NW; i += stride) {
    wbf[i] = f2bf(Wz[i]);
    wbf[NW + i] = f2bf(Wr[i]);
    wbf[2 * NW + i] = f2bf(Ws[i]);
  }
  // s0 -> frag-layout bf16: [bg][kc][lane]; b = bg*16 + (l&15), k = kc*32 + (l>>4)*8
  for (int f = tid; f < 4 * 32 * 64; f += stride) {
    int kc = (f >> 6) & 31, l = f & 63;
    int b = (f >> 11) * 16 + (l & 15);
    int k = kc * 32 + (l >> 4) * 8;
    const float* sp = s0 + (u64)b * H_ + k;
    ushort4 lo, hi;
    lo.x = f2bf(sp[0]); lo.y = f2bf(sp[1]); lo.z = f2bf(sp[2]); lo.w = f2bf(sp[3]);
    hi.x = f2bf(sp[4]); hi.y = f2bf(sp[5]); hi.z = f2bf(sp[6]); hi.w = f2bf(sp[7]);
    ushort4* dst = (ushort4*)(ws + OFF_SBF + (u64)f * 16);
    dst[0] = lo; dst[1] = hi;
  }
}

// ---- per-group distributed flag barrier (64 members, no RMW, no fences;
// shared state travels via sc1 agent-scope ops that bypass L1/L2) ----
__device__ __forceinline__ void bar_signal(unsigned* flags, int bg, int hs, unsigned bidx) {
  asm volatile("s_waitcnt vmcnt(0)" ::: "memory");  // drain sc1 state stores (per wave)
  __syncthreads();                                   // all waves drained
  if (threadIdx.x == 0)
    __hip_atomic_store(flags + (u64)(bg * NMEM + hs) * 32, bidx,
                       __ATOMIC_RELAXED, __HIP_MEMORY_SCOPE_AGENT);
}
__device__ __forceinline__ void bar_poll(unsigned* flags, int bg, unsigned bidx) {
  if (threadIdx.x < NMEM) {
    while (__hip_atomic_load(flags + (u64)(bg * NMEM + threadIdx.x) * 32,
                             __ATOMIC_RELAXED, __HIP_MEMORY_SCOPE_AGENT) < bidx)
      __builtin_amdgcn_s_sleep(1);
  }
  __syncthreads();
}

#define SWZ(row, byteInRow, rowShift) \
  (((((row) << (rowShift)) + (byteInRow))) ^ (((row) & 7) << 4))

__global__ __launch_bounds__(NTHR, 1) void scan_kernel(
    const float* __restrict__ x, const float* __restrict__ mask,
    const float* __restrict__ bz, const float* __restrict__ br,
    const float* __restrict__ bs, const float* __restrict__ s0,
    char* __restrict__ ws, float* __restrict__ out) {

  __shared__ u16 u_lds[3 * 16 * 1024];   // 96KB U slices (swizzled, resident)
  __shared__ u16 w_lds[3 * 16 * 512];    // 48KB W slices (swizzled, resident)
  __shared__ f32x4 red[4][2][64];        // 8KB  cross-wave K-split reduction
  __shared__ u16 tbf[16][16];            // 512B wave-0 bf16 transpose tile
  __shared__ float tf32[16][16];         // 1KB  wave-0 f32 transpose tile

  u64* fsbf = (u64*)(ws + OFF_SBF);
  u64* frs  = (u64*)(ws + OFF_RS);
  const u16* ubf = (const u16*)(ws + OFF_U);
  const u16* wbf = (const u16*)(ws + OFF_W);
  unsigned* flags = (unsigned*)(ws + OFF_FLG);

  const int tid = threadIdx.x;
  const int jb = blockIdx.x;
  const int bg = jb & 3;          // batch group (16 batches)
  const int hs = jb >> 2;         // h-slice index (16 h columns)
  const int h0 = hs * 16;
  const int lane = tid & 63;
  const int wave = tid >> 6;
  const int ln15 = lane & 15;
  const int kg = lane >> 4;
  const int h = h0 + ln15;

  // one-time LDS preload of U and W slices for this h-slice
  for (int e = tid * 8; e < 3 * 16 * 1024; e += NTHR * 8) {
    int row = e >> 10, k = e & 1023;
    int g = row >> 4, hi = row & 15;
    uint4 v = *(const uint4*)(ubf + ((u64)(g * H_ + h0 + hi) * H_ + k));
    *(uint4*)((char*)u_lds + SWZ(row, (k << 1), 11)) = v;
  }
  for (int e = tid * 8; e < 3 * 16 * 512; e += NTHR * 8) {
    int row = e >> 9, k = e & 511;
    int g = row >> 4, hi = row & 15;
    uint4 v = *(const uint4*)(wbf + ((u64)(g * H_ + h0 + hi) * I_ + k));
    *(uint4*)((char*)w_lds + SWZ(row, (k << 1), 10)) = v;
  }
  const float bzv = bz[h];
  const float brv = br[h];
  const float bsv = bs[h];
  float sreg[4];   // meaningful in wave 0 only
  #pragma unroll
  for (int j = 0; j < 4; ++j)
    sreg[j] = s0[(u64)(bg * 16 + kg * 4 + j) * H_ + h];
  __syncthreads();

  // x A-frags for this step: wave covers x-kc = wave*4 .. wave*4+4 (K_x = 512)
  s16x8 xf[4];
  {
    #pragma unroll
    for (int i = 0; i < 4; ++i) {
      int kc = wave * 4 + i;
      const float* xp = x + ((u64)(bg * 16 + ln15) * T_ + 0) * I_ + kc * 32 + kg * 8;
      xf[i] = pack8(*(const float4*)xp, *(const float4*)(xp + 4));
    }
  }
  unsigned bidx = 0;

  for (int t = 0; t < T_; ++t) {
    float mv[4];
    #pragma unroll
    for (int j = 0; j < 4; ++j) mv[j] = mask[(u64)(bg * 16 + kg * 4 + j) * T_ + t];

    // ---------------- phase 1: z, r (K = 1024 state + 512 x) ----------------
    u64 aS[16];
    {
      const u64* base = fsbf + ((u64)bg * 32 + wave * 8) * 128 + lane * 2;
      #pragma unroll
      for (int q = 0; q < 8; ++q) {
        aS[2 * q]     = __hip_atomic_load(base + q * 128,     __ATOMIC_RELAXED, __HIP_MEMORY_SCOPE_AGENT);
        aS[2 * q + 1] = __hip_atomic_load(base + q * 128 + 1, __ATOMIC_RELAXED, __HIP_MEMORY_SCOPE_AGENT);
      }
    }
    f32x4 accz = {0.f,0.f,0.f,0.f}, accr = {0.f,0.f,0.f,0.f};
    #pragma unroll
    for (int q = 0; q < 8; ++q) {
      FR u; u.q[0] = aS[2 * q]; u.q[1] = aS[2 * q + 1];
      const int cb = (wave * 8 + q) * 64 + kg * 16;
      s16x8 b0 = *(const s16x8*)((const char*)u_lds + SWZ(ln15, cb, 11));
      s16x8 b1 = *(const s16x8*)((const char*)u_lds + SWZ(16 + ln15, cb, 11));
      accz = __builtin_amdgcn_mfma_f32_16x16x32_bf16(u.v, b0, accz, 0, 0, 0);
      accr = __builtin_amdgcn_mfma_f32_16x16x32_bf16(u.v, b1, accr, 0, 0, 0);
    }
    #pragma unroll
    for (int i = 0; i < 4; ++i) {
      const int cb = (wave * 4 + i) * 64 + kg * 16;
      s16x8 w0 = *(const s16x8*)((const char*)w_lds + SWZ(ln15, cb, 10));
      s16x8 w1 = *(const s16x8*)((const char*)w_lds + SWZ(16 + ln15, cb, 10));
      accz = __builtin_amdgcn_mfma_f32_16x16x32_bf16(xf[i], w0, accz, 0, 0, 0);
      accr = __builtin_amdgcn_mfma_f32_16x16x32_bf16(xf[i], w1, accr, 0, 0, 0);
    }
    red[wave][0][lane] = accz;
    red[wave][1][lane] = accr;
    __syncthreads();
    float zv[4];   // wave 0 only
    if (wave == 0) {
      f32x4 az = red[0][0][lane], ar = red[0][1][lane];
      #pragma unroll
      for (int w = 1; w < 4; ++w) { az += red[w][0][lane]; ar += red[w][1][lane]; }
      #pragma unroll
      for (int j = 0; j < 4; ++j) {
        float z = 1.f / (1.f + __expf(-(az[j] + bzv)));
        float r = 1.f / (1.f + __expf(-(ar[j] + brv)));
        zv[j] = z;
        tbf[kg * 4 + j][ln15] = f2bf(sreg[j] * r);
      }
      if (lane < 32) {  // rs tile -> frag layout, sc1 store
        FR u;
        u.v = *(const s16x8*)&tbf[lane & 15][(lane >> 4) * 8];
        u64* dst = frs + ((u64)bg * 32 + (hs >> 1)) * 128 + ((u64)lane + 32 * (hs & 1)) * 2;
        __hip_atomic_store(dst,     u.q[0], __ATOMIC_RELAXED, __HIP_MEMORY_SCOPE_AGENT);
        __hip_atomic_store(dst + 1, u.q[1], __ATOMIC_RELAXED, __HIP_MEMORY_SCOPE_AGENT);
      }
    }
    ++bidx;
    bar_signal(flags, bg, hs, bidx);
    bar_poll(flags, bg, bidx);

    // ---------------- phase 2: s_hat, state update ----------------
    u64 aR[16];
    {
      const u64* base = frs + ((u64)bg * 32 + wave * 8) * 128 + lane * 2;
      #pragma unroll
      for (int q = 0; q < 8; ++q) {
        aR[2 * q]     = __hip_atomic_load(base + q * 128,     __ATOMIC_RELAXED, __HIP_MEMORY_SCOPE_AGENT);
        aR[2 * q + 1] = __hip_atomic_load(base + q * 128 + 1, __ATOMIC_RELAXED, __HIP_MEMORY_SCOPE_AGENT);
      }
    }
    f32x4 accs = {0.f,0.f,0.f,0.f};
    #pragma unroll
    for (int q = 0; q < 8; ++q) {
      FR u; u.q[0] = aR[2 * q]; u.q[1] = aR[2 * q + 1];
      const int cb = (wave * 8 + q) * 64 + kg * 16;
      s16x8 b2 = *(const s16x8*)((const char*)u_lds + SWZ(32 + ln15, cb, 11));
      accs = __builtin_amdgcn_mfma_f32_16x16x32_bf16(u.v, b2, accs, 0, 0, 0);
    }
    #pragma unroll
    for (int i = 0; i < 4; ++i) {
      const int cb = (wave * 4 + i) * 64 + kg * 16;
      s16x8 w2 = *(const s16x8*)((const char*)w_lds + SWZ(32 + ln15, cb, 10));
      accs = __builtin_amdgcn_mfma_f32_16x16x32_bf16(xf[i], w2, accs, 0, 0, 0);
    }
    red[wave][0][lane] = accs;
    __syncthreads();
    if (wave == 0) {
      f32x4 as_ = red[0][0][lane];
      #pragma unroll
      for (int w = 1; w < 4; ++w) as_ += red[w][0][lane];
      #pragma unroll
      for (int j = 0; j < 4; ++j) {
        float shat = fmaxf(as_[j] + bsv, 0.f);
        float sn = (1.f - zv[j]) * sreg[j] + zv[j] * shat;
        float sf = sreg[j] + mv[j] * (sn - sreg[j]);
        sreg[j] = sf;
        tf32[kg * 4 + j][ln15] = sf;
        tbf[kg * 4 + j][ln15] = f2bf(sf);
      }
      {  // coalesced out store: 64B contiguous per (b,t)
        f32x4 o = *(const f32x4*)&tf32[lane >> 2][(lane & 3) * 4];
        f32x4* op = (f32x4*)(out + ((u64)(bg * 16 + (lane >> 2)) * T_ + t) * H_ + h0 + (lane & 3) * 4);
        __builtin_nontemporal_store(o, op);
      }
      if (lane < 32) {  // new s tile -> frag layout, sc1 store
        FR u;
        u.v = *(const s16x8*)&tbf[lane & 15][(lane >> 4) * 8];
        u64* dst = fsbf + ((u64)bg * 32 + (hs >> 1)) * 128 + ((u64)lane + 32 * (hs & 1)) * 2;
        __hip_atomic_store(dst,     u.q[0], __ATOMIC_RELAXED, __HIP_MEMORY_SCOPE_AGENT);
        __hip_atomic_store(dst + 1, u.q[1], __ATOMIC_RELAXED, __HIP_MEMORY_SCOPE_AGENT);
      }
    }
    ++bidx;
    bar_signal(flags, bg, hs, bidx);
    if (t + 1 < T_) {  // overlap next step's x A-frag load with barrier gap
      #pragma unroll
      for (int i = 0; i < 4; ++i) {
        int kc = wave * 4 + i;
        const float* xp = x + ((u64)(bg * 16 + ln15) * T_ + (t + 1)) * I_ + kc * 32 + kg * 8;
        xf[i] = pack8(*(const float4*)xp, *(const float4*)(xp + 4));
      }
    }
    bar_poll(flags, bg, bidx);
  }
}

extern "C" void kernel_launch(void* const* d_in, const int* in_sizes, int n_in,
                              void* d_out, int out_size, void* d_ws, size_t ws_size,
                              hipStream_t stream) {
  const float* x   = (const float*)d_in[0];
  const float* msk = (const float*)d_in[1];
  const float* s0  = (const float*)d_in[2];
  const float* Ws_ = (const float*)d_in[3];
  const float* Wr_ = (const float*)d_in[4];
  const float* Wz_ = (const float*)d_in[5];
  const float* Us_ = (const float*)d_in[6];
  const float* Ur_ = (const float*)d_in[7];
  const float* Uz_ = (const float*)d_in[8];
  const float* bs_ = (const float*)d_in[9];
  const float* br_ = (const float*)d_in[10];
  const float* bz_ = (const float*)d_in[11];
  float* out = (float*)d_out;
  char* ws = (char*)d_ws;

  (void)hipMemsetAsync(d_ws, 0, 32768, stream);  // barrier flags
  hipLaunchKernelGGL(prep_kernel, dim3(1024), dim3(256), 0, stream,
                     s0, Wz_, Wr_, Ws_, Uz_, Ur_, Us_, ws);
  hipLaunchKernelGGL(scan_kernel, dim3(NBLK), dim3(NTHR), 0, stream,
                     x, msk, bz_, br_, bs_, s0, ws, out);
}